// Round 19
// baseline (232.126 us; speedup 1.0000x reference)
//
#include <hip/hip_runtime.h>
#include <hip/hip_bf16.h>

// Attention_65541200937161: B=16, N=1024, E=512, H=8, DH=64
// Round 19: r18 with ONE change — d prefetched TWO tiles ahead (two static
// register sets alternating by tile parity). Tests the last latency theory:
// d(t+1)-after-softmax(t) gave only ~600cyc cover; distance 2 gives ~2500.

#define Bc  16
#define Nc  1024
#define Ec  512
#define Hc  8
#define DHc 64

typedef float  f32x4  __attribute__((ext_vector_type(4)));
typedef int    i32x4  __attribute__((ext_vector_type(4)));
typedef short  s16x4  __attribute__((ext_vector_type(4)));
typedef short  s16x8  __attribute__((ext_vector_type(8)));
typedef __bf16 bf16x8 __attribute__((ext_vector_type(8)));

static __device__ __forceinline__ f32x4 mfma16(s16x8 a, s16x8 b, f32x4 c) {
    return __builtin_amdgcn_mfma_f32_16x16x32_bf16(
        __builtin_bit_cast(bf16x8, a), __builtin_bit_cast(bf16x8, b), c, 0, 0, 0);
}

static __device__ __forceinline__ unsigned short f2bf(float f) {
    return __builtin_bit_cast(unsigned short, __float2bfloat16(f));
}

static __device__ __forceinline__ s16x8 pack_bf16(f32x4 a, f32x4 b) {
    s16x8 r;
    r[0] = (short)f2bf(a[0]); r[1] = (short)f2bf(a[1]);
    r[2] = (short)f2bf(a[2]); r[3] = (short)f2bf(a[3]);
    r[4] = (short)f2bf(b[0]); r[5] = (short)f2bf(b[1]);
    r[6] = (short)f2bf(b[2]); r[7] = (short)f2bf(b[3]);
    return r;
}

// async global->LDS, 16B per lane (GEMMs only).
static __device__ __forceinline__ void gld16(const void* g, void* l) {
    __builtin_amdgcn_global_load_lds(
        (const __attribute__((address_space(1))) void*)g,
        (__attribute__((address_space(3))) void*)l, 16, 0, 0);
}

// barrier: own LDS reads+writes drained (lgkm only), no vmem drain.
static __device__ __forceinline__ void lds_publish_barrier() {
    asm volatile("s_waitcnt lgkmcnt(0)" ::: "memory");
    __builtin_amdgcn_s_barrier();
    asm volatile("" ::: "memory");
}

// ---------------- W f32 -> bf16 pre-conversion (4 x 512x512) ----------------
__global__ __launch_bounds__(256) void wcvt_kernel(
    const float* __restrict__ Wq, const float* __restrict__ Wk,
    const float* __restrict__ Wv, const float* __restrict__ Wp,
    unsigned short* __restrict__ wbf)
{
    const int seg = blockIdx.x >> 7;
    const float* src = seg == 0 ? Wq : (seg == 1 ? Wk : (seg == 2 ? Wv : Wp));
    const int g = (blockIdx.x & 127) * 256 + threadIdx.x;
    const float* p = src + (size_t)g * 8;
    f32x4 a = *(const f32x4*)p, b = *(const f32x4*)(p + 4);
    *(s16x8*)(wbf + (size_t)seg * 262144 + (size_t)g * 8) = pack_bf16(a, b);
}

// ---------------- fused q/k/v projection (bf16 W) ---------------------------
__global__ __launch_bounds__(256) void proj3_kernel(
    const float* __restrict__ qi, const float* __restrict__ ki,
    const float* __restrict__ vi, const unsigned short* __restrict__ wbf,
    const float* __restrict__ bq, const float* __restrict__ bk,
    const float* __restrict__ bv,
    unsigned short* __restrict__ qo, unsigned short* __restrict__ ko,
    unsigned short* __restrict__ vo)
{
    const int z = blockIdx.z;
    const float* Af = z == 0 ? qi : (z == 1 ? ki : vi);
    const unsigned short* Wb = wbf + (size_t)z * 262144;
    const float* bias = z == 0 ? bq : (z == 1 ? bk : bv);
    unsigned short* out = z == 0 ? qo : (z == 1 ? ko : vo);
    const int mode = (z == 2) ? 1 : 0;

    __shared__ float As_raw[128 * 32];
    __shared__ unsigned short Bsb[128 * 32];

    const int tid = threadIdx.x;
    const int w = tid >> 6, lane = tid & 63;
    const int lr = lane & 15, grp = lane >> 4;
    const int wr = w >> 1, wc = w & 1;
    const int m0 = blockIdx.x * 128, n0 = blockIdx.y * 128;

    f32x4 acc[4][4];
#pragma unroll
    for (int i = 0; i < 4; ++i)
#pragma unroll
        for (int j = 0; j < 4; ++j) acc[i][j] = (f32x4)(0.0f);

    const int h8 = lane >> 3, l8 = lane & 7;
    const int fcol = ((l8 ^ h8) << 2);
    const int h4 = lane >> 2, l4 = lane & 3;
    const int bcol = ((l4 ^ (h4 & 3)) << 3);
    const int o0 = (((grp << 1) ^ (lr & 7)) << 2);
    const int ob = ((grp ^ (lr & 3)) << 3);

    for (int k0 = 0; k0 < Ec; k0 += 32) {
        __syncthreads();
#pragma unroll
        for (int i = 0; i < 4; ++i) {
            const int chunk = i * 4 + w;
            const int row = chunk * 8 + h8;
            gld16(Af + (size_t)(m0 + row) * Ec + k0 + fcol,
                  (char*)As_raw + chunk * 1024 + lane * 16);
        }
#pragma unroll
        for (int i = 0; i < 2; ++i) {
            const int chunk = i * 4 + w;
            const int row = chunk * 16 + h4;
            gld16(Wb + (size_t)(n0 + row) * Ec + k0 + bcol,
                  (char*)Bsb + chunk * 1024 + lane * 16);
        }
        __syncthreads();

        s16x8 afr[4], bfr[4];
#pragma unroll
        for (int mi = 0; mi < 4; ++mi) {
            const float* p = As_raw + (wr * 64 + mi * 16 + lr) * 32;
            afr[mi] = pack_bf16(*(const f32x4*)(p + o0), *(const f32x4*)(p + (o0 ^ 4)));
        }
#pragma unroll
        for (int ni = 0; ni < 4; ++ni)
            bfr[ni] = *(const s16x8*)(Bsb + (wc * 64 + ni * 16 + lr) * 32 + ob);
#pragma unroll
        for (int mi = 0; mi < 4; ++mi)
#pragma unroll
            for (int ni = 0; ni < 4; ++ni)
                acc[mi][ni] = mfma16(afr[mi], bfr[ni], acc[mi][ni]);
    }

#pragma unroll
    for (int mi = 0; mi < 4; ++mi) {
        const int mbase = m0 + wr * 64 + mi * 16 + grp * 4;
#pragma unroll
        for (int ni = 0; ni < 4; ++ni) {
            const int f = n0 + wc * 64 + ni * 16 + lr;
            const float bi = bias[f];
            f32x4 vv = acc[mi][ni];
            const int hh = f >> 6, dh = f & 63;
            if (mode == 0) {
#pragma unroll
                for (int r = 0; r < 4; ++r) {
                    const int m = mbase + r;
                    out[(((size_t)(m >> 10) * Hc + hh) * Nc + (m & (Nc - 1))) * DHc + dh] =
                        f2bf(vv[r] + bi);
                }
            } else {
                const int bb = mbase >> 10, n = mbase & (Nc - 1);
                s16x4 pk;
#pragma unroll
                for (int r = 0; r < 4; ++r) pk[r] = (short)f2bf(vv[r] + bi);
                *(s16x4*)&out[(((size_t)bb * Hc + hh) * DHc + dh) * Nc + n] = pk;
            }
        }
    }
}

// ---------------- output projection (bf16 A and bf16 W) ---------------------
__global__ __launch_bounds__(256) void outproj_kernel(
    const unsigned short* __restrict__ Ab, const unsigned short* __restrict__ Wb,
    const float* __restrict__ bias, float* __restrict__ out)
{
    __shared__ unsigned short Asb[128 * 32];
    __shared__ unsigned short Bsb[128 * 32];

    const int tid = threadIdx.x;
    const int w = tid >> 6, lane = tid & 63;
    const int lr = lane & 15, grp = lane >> 4;
    const int wr = w >> 1, wc = w & 1;
    const int m0 = blockIdx.x * 128, n0 = blockIdx.y * 128;

    f32x4 acc[4][4];
#pragma unroll
    for (int i = 0; i < 4; ++i)
#pragma unroll
        for (int j = 0; j < 4; ++j) acc[i][j] = (f32x4)(0.0f);

    const int h4 = lane >> 2, l4 = lane & 3;
    const int bcol = ((l4 ^ (h4 & 3)) << 3);
    const int ob = ((grp ^ (lr & 3)) << 3);

    for (int k0 = 0; k0 < Ec; k0 += 32) {
        __syncthreads();
#pragma unroll
        for (int i = 0; i < 2; ++i) {
            const int chunk = i * 4 + w;
            const int row = chunk * 16 + h4;
            gld16(Ab + (size_t)(m0 + row) * Ec + k0 + bcol,
                  (char*)Asb + chunk * 1024 + lane * 16);
            gld16(Wb + (size_t)(n0 + row) * Ec + k0 + bcol,
                  (char*)Bsb + chunk * 1024 + lane * 16);
        }
        __syncthreads();

        s16x8 afr[4], bfr[4];
#pragma unroll
        for (int mi = 0; mi < 4; ++mi)
            afr[mi] = *(const s16x8*)(Asb + (wr * 64 + mi * 16 + lr) * 32 + ob);
#pragma unroll
        for (int ni = 0; ni < 4; ++ni)
            bfr[ni] = *(const s16x8*)(Bsb + (wc * 64 + ni * 16 + lr) * 32 + ob);
#pragma unroll
        for (int mi = 0; mi < 4; ++mi)
#pragma unroll
            for (int ni = 0; ni < 4; ++ni)
                acc[mi][ni] = mfma16(afr[mi], bfr[ni], acc[mi][ni]);
    }

#pragma unroll
    for (int mi = 0; mi < 4; ++mi) {
        const int mbase = m0 + wr * 64 + mi * 16 + grp * 4;
#pragma unroll
        for (int ni = 0; ni < 4; ++ni) {
            const int f = n0 + wc * 64 + ni * 16 + lr;
            const float bi = bias[f];
            f32x4 vv = acc[mi][ni];
#pragma unroll
            for (int r = 0; r < 4; ++r)
                out[(size_t)(mbase + r) * Ec + f] = vv[r] + bi;
        }
    }
}

// ---------------- attention v15: r18 + d prefetch distance 2 ----------------
// 4 waves x 32 q. dv sets A/B alternate by tile parity: tile t consumes set
// (t&1) and refills it with d(t+2). Static indexing via unroll-2 parity branch.
__global__ __launch_bounds__(256) void attn_kernel(
    const unsigned short* __restrict__ qh, const unsigned short* __restrict__ kh,
    const unsigned short* __restrict__ vt, const float* __restrict__ dmat,
    unsigned short* __restrict__ xh)
{
    __shared__ unsigned short K_lds[2][64 * 64];  // 2 x 8 KB
    __shared__ unsigned short V_lds[2][64 * 64];  // 2 x 8 KB
    __shared__ unsigned short P_lds[4][32][72];   // 18 KB

    const int lin = blockIdx.x;                   // 1024 blocks
    const int j = lin >> 3;
    const int h = j & 7;
    const int qt = (j >> 3) & 7;
    const int b = ((lin & 7) << 1) | (j >> 6);

    const int tid = threadIdx.x;
    const int w = tid >> 6, lane = tid & 63;
    const int lr = lane & 15, grp = lane >> 4;
    const int h8 = lane >> 3, l8 = lane & 7;
    const int q0 = qt * 128;
    const int bh = b * Hc + h;
    const int qw = q0 + w * 32;
    const int kofs = grp * 4;
    const int scol = (l8 ^ h8) * 8;
    const float* dbase0 = dmat + ((size_t)b * Nc + qw + lr) * Nc;
    const float* dbase1 = dbase0 + (size_t)16 * Nc;

    const float LOG2E = 1.4426950408889634f;
    const float SC    = 0.125f * LOG2E;
    const float MC    = -4.0f * LOG2E;

    s16x8 bq0[2], bq1[2];
#pragma unroll
    for (int ks = 0; ks < 2; ++ks) {
        bq0[ks] = *reinterpret_cast<const s16x8*>(
            qh + ((size_t)bh * Nc + qw + lr) * DHc + ks * 32 + grp * 8);
        bq1[ks] = *reinterpret_cast<const s16x8*>(
            qh + ((size_t)bh * Nc + qw + 16 + lr) * DHc + ks * 32 + grp * 8);
    }

    f32x4 acc0[4], acc1[4];
#pragma unroll
    for (int c = 0; c < 4; ++c) { acc0[c] = (f32x4)(0.0f); acc1[c] = (f32x4)(0.0f); }
    float lsum0 = 0.f, lsum1 = 0.f;

    const int NT = Nc / 64;
    i32x4 kst[2], vst[2];
    // prologue: tile 0 -> regs -> buf[0]; tile 1 -> regs; d(0)->A, d(1)->B.
#pragma unroll
    for (int i = 0; i < 2; ++i) {
        const int ch = w + i * 4;
        kst[i] = *reinterpret_cast<const i32x4*>(
            kh + ((size_t)bh * Nc + ch * 8 + h8) * DHc + scol);
        vst[i] = *reinterpret_cast<const i32x4*>(
            vt + ((size_t)bh * DHc + ch * 8 + h8) * Nc + scol);
    }
#pragma unroll
    for (int i = 0; i < 2; ++i) {
        const int ch = w + i * 4;
        *reinterpret_cast<i32x4*>((char*)K_lds[0] + ch * 1024 + lane * 16) = kst[i];
        *reinterpret_cast<i32x4*>((char*)V_lds[0] + ch * 1024 + lane * 16) = vst[i];
    }
#pragma unroll
    for (int i = 0; i < 2; ++i) {
        const int ch = w + i * 4;
        kst[i] = *reinterpret_cast<const i32x4*>(
            kh + ((size_t)bh * Nc + 64 + ch * 8 + h8) * DHc + scol);
        vst[i] = *reinterpret_cast<const i32x4*>(
            vt + ((size_t)bh * DHc + ch * 8 + h8) * Nc + 64 + scol);
    }
    f32x4 dvA0[4], dvA1[4], dvB0[4], dvB1[4];
#pragma unroll
    for (int c = 0; c < 4; ++c) {
        dvA0[c] = *reinterpret_cast<const f32x4*>(dbase0 + c * 16 + kofs);
        dvA1[c] = *reinterpret_cast<const f32x4*>(dbase1 + c * 16 + kofs);
        dvB0[c] = *reinterpret_cast<const f32x4*>(dbase0 + 64 + c * 16 + kofs);
        dvB1[c] = *reinterpret_cast<const f32x4*>(dbase1 + 64 + c * 16 + kofs);
    }

#define SOFTMAX_RELOAD(DV0, DV1)                                               \
    {                                                                          \
        _Pragma("unroll")                                                      \
        for (int c = 0; c < 4; ++c) {                                          \
            s16x4 pk0, pk1;                                                    \
            _Pragma("unroll")                                                  \
            for (int r = 0; r < 4; ++r) {                                      \
                const float dl0 = fmaf(DV0[c][r], LOG2E, MC);                  \
                const float p0 = __builtin_amdgcn_exp2f(fmaf(lgt0[c][r], SC, dl0)); \
                lsum0 += p0;                                                   \
                pk0[r] = (short)f2bf(p0 * DV0[c][r]);                          \
                const float dl1 = fmaf(DV1[c][r], LOG2E, MC);                  \
                const float p1 = __builtin_amdgcn_exp2f(fmaf(lgt1[c][r], SC, dl1)); \
                lsum1 += p1;                                                   \
                pk1[r] = (short)f2bf(p1 * DV1[c][r]);                          \
            }                                                                  \
            *reinterpret_cast<s16x4*>(&P_lds[w][lr][c * 16 + kofs]) = pk0;     \
            *reinterpret_cast<s16x4*>(&P_lds[w][16 + lr][c * 16 + kofs]) = pk1;\
        }                                                                      \
        if (kt + 2 < NT) {                                                     \
            const int k2 = (kt + 2) * 64;                                      \
            _Pragma("unroll")                                                  \
            for (int c = 0; c < 4; ++c) {                                      \
                DV0[c] = *reinterpret_cast<const f32x4*>(dbase0 + k2 + c * 16 + kofs); \
                DV1[c] = *reinterpret_cast<const f32x4*>(dbase1 + k2 + c * 16 + kofs); \
            }                                                                  \
        }                                                                      \
    }

#pragma unroll 2
    for (int kt = 0; kt < NT; ++kt) {
        const int cur = kt & 1;
        lds_publish_barrier();
        if (kt + 1 < NT) {
#pragma unroll
            for (int i = 0; i < 2; ++i) {
                const int ch = w + i * 4;
                *reinterpret_cast<i32x4*>((char*)K_lds[cur ^ 1] + ch * 1024 + lane * 16) = kst[i];
                *reinterpret_cast<i32x4*>((char*)V_lds[cur ^ 1] + ch * 1024 + lane * 16) = vst[i];
            }
        }
        if (kt + 2 < NT) {
            const int k2 = (kt + 2) * 64;
#pragma unroll
            for (int i = 0; i < 2; ++i) {
                const int ch = w + i * 4;
                kst[i] = *reinterpret_cast<const i32x4*>(
                    kh + ((size_t)bh * Nc + k2 + ch * 8 + h8) * DHc + scol);
                vst[i] = *reinterpret_cast<const i32x4*>(
                    vt + ((size_t)bh * DHc + ch * 8 + h8) * Nc + k2 + scol);
            }
        }

        // QK^T swapped
        f32x4 lgt0[4], lgt1[4];
#pragma unroll
        for (int c = 0; c < 4; ++c) { lgt0[c] = (f32x4)(0.0f); lgt1[c] = (f32x4)(0.0f); }
        __builtin_amdgcn_s_setprio(1);
#pragma unroll
        for (int ks = 0; ks < 2; ++ks) {
#pragma unroll
            for (int c = 0; c < 4; ++c) {
                const int row = c * 16 + lr;
                const int slot = (4 * ks + grp) ^ (lr & 7);
                s16x8 ak = *reinterpret_cast<const s16x8*>(
                    (const char*)K_lds[cur] + row * 128 + slot * 16);
                lgt0[c] = mfma16(ak, bq0[ks], lgt0[c]);
                lgt1[c] = mfma16(ak, bq1[ks], lgt1[c]);
            }
        }
        __builtin_amdgcn_s_setprio(0);

        if ((kt & 1) == 0) SOFTMAX_RELOAD(dvA0, dvA1)
        else               SOFTMAX_RELOAD(dvB0, dvB1)

        // PV
        __builtin_amdgcn_s_setprio(1);
#pragma unroll
        for (int ks = 0; ks < 2; ++ks) {
            s16x8 pa0 = *reinterpret_cast<const s16x8*>(&P_lds[w][lr][ks * 32 + grp * 8]);
            s16x8 pa1 = *reinterpret_cast<const s16x8*>(&P_lds[w][16 + lr][ks * 32 + grp * 8]);
#pragma unroll
            for (int c = 0; c < 4; ++c) {
                const int row = c * 16 + lr;
                const int slot = (4 * ks + grp) ^ (lr & 7);
                s16x8 bv = *reinterpret_cast<const s16x8*>(
                    (const char*)V_lds[cur] + row * 128 + slot * 16);
                acc0[c] = mfma16(pa0, bv, acc0[c]);
                acc1[c] = mfma16(pa1, bv, acc1[c]);
            }
        }
        __builtin_amdgcn_s_setprio(0);
    }
#undef SOFTMAX_RELOAD

    // denominators
    lsum0 += __shfl_xor(lsum0, 16, 64);
    lsum0 += __shfl_xor(lsum0, 32, 64);
    lsum1 += __shfl_xor(lsum1, 16, 64);
    lsum1 += __shfl_xor(lsum1, 32, 64);
    const float invd0 = 1.0f / lsum0, invd1 = 1.0f / lsum1;
    float inv0[4], inv1[4];
#pragma unroll
    for (int r = 0; r < 4; ++r) {
        inv0[r] = __shfl(invd0, grp * 4 + r, 64);
        inv1[r] = __shfl(invd1, grp * 4 + r, 64);
    }
#pragma unroll
    for (int c = 0; c < 4; ++c)
#pragma unroll
        for (int r = 0; r < 4; ++r) {
            xh[((size_t)b * Nc + qw + grp * 4 + r) * Ec + h * DHc + c * 16 + lr] =
                f2bf(acc0[c][r] * inv0[r]);
            xh[((size_t)b * Nc + qw + 16 + grp * 4 + r) * Ec + h * DHc + c * 16 + lr] =
                f2bf(acc1[c][r] * inv1[r]);
        }
}

extern "C" void kernel_launch(void* const* d_in, const int* in_sizes, int n_in,
                              void* d_out, int out_size, void* d_ws, size_t ws_size,
                              hipStream_t stream)
{
    (void)in_sizes; (void)n_in; (void)out_size; (void)ws_size;
    const float* q  = (const float*)d_in[0];
    const float* k  = (const float*)d_in[1];
    const float* v  = (const float*)d_in[2];
    const float* dm = (const float*)d_in[3];
    const float* Wq = (const float*)d_in[4];
    const float* bq = (const float*)d_in[5];
    const float* Wk = (const float*)d_in[6];
    const float* bk = (const float*)d_in[7];
    const float* Wv = (const float*)d_in[8];
    const float* bv = (const float*)d_in[9];
    const float* Wp = (const float*)d_in[10];
    const float* bp = (const float*)d_in[11];
    float* out = (float*)d_out;

    const size_t sz = (size_t)Bc * Hc * Nc * DHc;   // 8,388,608 elements
    unsigned short* qhb = (unsigned short*)d_ws;
    unsigned short* khb = qhb + sz;
    unsigned short* vtb = khb + sz;
    unsigned short* xhb = vtb + sz;
    unsigned short* wbf = xhb + sz;                 // 4 x 262144 bf16 = 2 MB

    wcvt_kernel<<<dim3(512), dim3(256), 0, stream>>>(Wq, Wk, Wv, Wp, wbf);
    proj3_kernel<<<dim3(Bc * Nc / 128, Ec / 128, 3), dim3(256), 0, stream>>>(
        q, k, v, wbf, bq, bk, bv, qhb, khb, vtb);
    attn_kernel<<<dim3(Bc * Hc * Nc / 128), dim3(256), 0, stream>>>(
        qhb, khb, vtb, dm, xhb);
    outproj_kernel<<<dim3(Bc * Nc / 128, Ec / 128), dim3(256), 0, stream>>>(
        xhb, wbf + (size_t)3 * 262144, bp, out);
}

// Round 20
// 157.048 us; speedup vs baseline: 1.4781x; 1.4781x over previous
//
#include <hip/hip_runtime.h>
#include <hip/hip_bf16.h>

// Attention_65541200937161: B=16, N=1024, E=512, H=8, DH=64
// Round 20: attention reverted to r18 champion (d-dist-2 regressed via VGPR
// 148 -> 11% occupancy). GEMM side: proj3 A-tile now reg-staged with f32->bf16
// cvt DURING staging (one cvt per element, direct s16x8 frag reads, A-LDS
// 16->8 KB). B path and outproj unchanged.

#define Bc  16
#define Nc  1024
#define Ec  512
#define Hc  8
#define DHc 64

typedef float  f32x4  __attribute__((ext_vector_type(4)));
typedef int    i32x4  __attribute__((ext_vector_type(4)));
typedef short  s16x4  __attribute__((ext_vector_type(4)));
typedef short  s16x8  __attribute__((ext_vector_type(8)));
typedef __bf16 bf16x8 __attribute__((ext_vector_type(8)));

static __device__ __forceinline__ f32x4 mfma16(s16x8 a, s16x8 b, f32x4 c) {
    return __builtin_amdgcn_mfma_f32_16x16x32_bf16(
        __builtin_bit_cast(bf16x8, a), __builtin_bit_cast(bf16x8, b), c, 0, 0, 0);
}

static __device__ __forceinline__ unsigned short f2bf(float f) {
    return __builtin_bit_cast(unsigned short, __float2bfloat16(f));
}

static __device__ __forceinline__ s16x8 pack_bf16(f32x4 a, f32x4 b) {
    s16x8 r;
    r[0] = (short)f2bf(a[0]); r[1] = (short)f2bf(a[1]);
    r[2] = (short)f2bf(a[2]); r[3] = (short)f2bf(a[3]);
    r[4] = (short)f2bf(b[0]); r[5] = (short)f2bf(b[1]);
    r[6] = (short)f2bf(b[2]); r[7] = (short)f2bf(b[3]);
    return r;
}

// async global->LDS, 16B per lane.
static __device__ __forceinline__ void gld16(const void* g, void* l) {
    __builtin_amdgcn_global_load_lds(
        (const __attribute__((address_space(1))) void*)g,
        (__attribute__((address_space(3))) void*)l, 16, 0, 0);
}

// barrier: own LDS reads+writes drained (lgkm only), no vmem drain.
static __device__ __forceinline__ void lds_publish_barrier() {
    asm volatile("s_waitcnt lgkmcnt(0)" ::: "memory");
    __builtin_amdgcn_s_barrier();
    asm volatile("" ::: "memory");
}

// ---------------- W f32 -> bf16 pre-conversion (4 x 512x512) ----------------
__global__ __launch_bounds__(256) void wcvt_kernel(
    const float* __restrict__ Wq, const float* __restrict__ Wk,
    const float* __restrict__ Wv, const float* __restrict__ Wp,
    unsigned short* __restrict__ wbf)
{
    const int seg = blockIdx.x >> 7;
    const float* src = seg == 0 ? Wq : (seg == 1 ? Wk : (seg == 2 ? Wv : Wp));
    const int g = (blockIdx.x & 127) * 256 + threadIdx.x;
    const float* p = src + (size_t)g * 8;
    f32x4 a = *(const f32x4*)p, b = *(const f32x4*)(p + 4);
    *(s16x8*)(wbf + (size_t)seg * 262144 + (size_t)g * 8) = pack_bf16(a, b);
}

// ---------------- fused q/k/v projection (bf16 W, bf16-staged A) ------------
// A: reg-staged f32->bf16 (one cvt/element, 8 KB tile). B: gld16 bf16 (8 KB).
// Both tiles [128][32] bf16, 64B rows, slot-XOR swizzle by row&3 (both sides).
__global__ __launch_bounds__(256) void proj3_kernel(
    const float* __restrict__ qi, const float* __restrict__ ki,
    const float* __restrict__ vi, const unsigned short* __restrict__ wbf,
    const float* __restrict__ bq, const float* __restrict__ bk,
    const float* __restrict__ bv,
    unsigned short* __restrict__ qo, unsigned short* __restrict__ ko,
    unsigned short* __restrict__ vo)
{
    const int z = blockIdx.z;
    const float* Af = z == 0 ? qi : (z == 1 ? ki : vi);
    const unsigned short* Wb = wbf + (size_t)z * 262144;
    const float* bias = z == 0 ? bq : (z == 1 ? bk : bv);
    unsigned short* out = z == 0 ? qo : (z == 1 ? ko : vo);
    const int mode = (z == 2) ? 1 : 0;

    __shared__ unsigned short Asb[128 * 32];       // 8 KB (bf16 A tile)
    __shared__ unsigned short Bsb[128 * 32];       // 8 KB (bf16 W tile)

    const int tid = threadIdx.x;
    const int w = tid >> 6, lane = tid & 63;
    const int lr = lane & 15, grp = lane >> 4;
    const int wr = w >> 1, wc = w & 1;
    const int m0 = blockIdx.x * 128, n0 = blockIdx.y * 128;

    f32x4 acc[4][4];
#pragma unroll
    for (int i = 0; i < 4; ++i)
#pragma unroll
        for (int j = 0; j < 4; ++j) acc[i][j] = (f32x4)(0.0f);

    // A staging geometry: thread t covers dest bytes t*16 of chunk (64 rows);
    // row = t>>2, 16B slot = t&3; source col swizzled by row&3 (inverse of ob).
    const int arow = tid >> 2, aslot = tid & 3;
    const int acol = ((aslot ^ (arow & 3)) << 3); // f32 elem idx in k-window
    // B staging (gld16): chunk = 16 rows; source col swizzled by row&3.
    const int h4 = lane >> 2, l4 = lane & 3;
    const int bcol = ((l4 ^ (h4 & 3)) << 3);
    // frag-read swizzle (row&3 == lr&3 for all frag rows):
    const int ob = ((grp ^ (lr & 3)) << 3);

    for (int k0 = 0; k0 < Ec; k0 += 32) {
        __syncthreads();
        // A: issue global loads (2 chunks of 64 rows)
        f32x4 a0[2], a1[2];
#pragma unroll
        for (int i = 0; i < 2; ++i) {
            const float* p = Af + (size_t)(m0 + i * 64 + arow) * Ec + k0 + acol;
            a0[i] = *(const f32x4*)p;
            a1[i] = *(const f32x4*)(p + 4);
        }
        // B: async gld16 (2 chunks)
#pragma unroll
        for (int i = 0; i < 2; ++i) {
            const int chunk = i * 4 + w;
            const int row = chunk * 16 + h4;
            gld16(Wb + (size_t)(n0 + row) * Ec + k0 + bcol,
                  (char*)Bsb + chunk * 1024 + lane * 16);
        }
        // A: cvt + publish (compiler inserts vmcnt waits for a0/a1)
#pragma unroll
        for (int i = 0; i < 2; ++i)
            *reinterpret_cast<s16x8*>((char*)Asb + i * 4096 + tid * 16) =
                pack_bf16(a0[i], a1[i]);
        __syncthreads();

        s16x8 afr[4], bfr[4];
#pragma unroll
        for (int mi = 0; mi < 4; ++mi)
            afr[mi] = *(const s16x8*)(Asb + (wr * 64 + mi * 16 + lr) * 32 + ob);
#pragma unroll
        for (int ni = 0; ni < 4; ++ni)
            bfr[ni] = *(const s16x8*)(Bsb + (wc * 64 + ni * 16 + lr) * 32 + ob);
#pragma unroll
        for (int mi = 0; mi < 4; ++mi)
#pragma unroll
            for (int ni = 0; ni < 4; ++ni)
                acc[mi][ni] = mfma16(afr[mi], bfr[ni], acc[mi][ni]);
    }

#pragma unroll
    for (int mi = 0; mi < 4; ++mi) {
        const int mbase = m0 + wr * 64 + mi * 16 + grp * 4;
#pragma unroll
        for (int ni = 0; ni < 4; ++ni) {
            const int f = n0 + wc * 64 + ni * 16 + lr;
            const float bi = bias[f];
            f32x4 vv = acc[mi][ni];
            const int hh = f >> 6, dh = f & 63;
            if (mode == 0) {
#pragma unroll
                for (int r = 0; r < 4; ++r) {
                    const int m = mbase + r;
                    out[(((size_t)(m >> 10) * Hc + hh) * Nc + (m & (Nc - 1))) * DHc + dh] =
                        f2bf(vv[r] + bi);
                }
            } else {
                const int bb = mbase >> 10, n = mbase & (Nc - 1);
                s16x4 pk;
#pragma unroll
                for (int r = 0; r < 4; ++r) pk[r] = (short)f2bf(vv[r] + bi);
                *(s16x4*)&out[(((size_t)bb * Hc + hh) * DHc + dh) * Nc + n] = pk;
            }
        }
    }
}

// ---------------- output projection (bf16 A and bf16 W) ---------------------
__global__ __launch_bounds__(256) void outproj_kernel(
    const unsigned short* __restrict__ Ab, const unsigned short* __restrict__ Wb,
    const float* __restrict__ bias, float* __restrict__ out)
{
    __shared__ unsigned short Asb[128 * 32];
    __shared__ unsigned short Bsb[128 * 32];

    const int tid = threadIdx.x;
    const int w = tid >> 6, lane = tid & 63;
    const int lr = lane & 15, grp = lane >> 4;
    const int wr = w >> 1, wc = w & 1;
    const int m0 = blockIdx.x * 128, n0 = blockIdx.y * 128;

    f32x4 acc[4][4];
#pragma unroll
    for (int i = 0; i < 4; ++i)
#pragma unroll
        for (int j = 0; j < 4; ++j) acc[i][j] = (f32x4)(0.0f);

    const int h4 = lane >> 2, l4 = lane & 3;
    const int bcol = ((l4 ^ (h4 & 3)) << 3);
    const int ob = ((grp ^ (lr & 3)) << 3);

    for (int k0 = 0; k0 < Ec; k0 += 32) {
        __syncthreads();
#pragma unroll
        for (int i = 0; i < 2; ++i) {
            const int chunk = i * 4 + w;
            const int row = chunk * 16 + h4;
            gld16(Ab + (size_t)(m0 + row) * Ec + k0 + bcol,
                  (char*)Asb + chunk * 1024 + lane * 16);
            gld16(Wb + (size_t)(n0 + row) * Ec + k0 + bcol,
                  (char*)Bsb + chunk * 1024 + lane * 16);
        }
        __syncthreads();

        s16x8 afr[4], bfr[4];
#pragma unroll
        for (int mi = 0; mi < 4; ++mi)
            afr[mi] = *(const s16x8*)(Asb + (wr * 64 + mi * 16 + lr) * 32 + ob);
#pragma unroll
        for (int ni = 0; ni < 4; ++ni)
            bfr[ni] = *(const s16x8*)(Bsb + (wc * 64 + ni * 16 + lr) * 32 + ob);
#pragma unroll
        for (int mi = 0; mi < 4; ++mi)
#pragma unroll
            for (int ni = 0; ni < 4; ++ni)
                acc[mi][ni] = mfma16(afr[mi], bfr[ni], acc[mi][ni]);
    }

#pragma unroll
    for (int mi = 0; mi < 4; ++mi) {
        const int mbase = m0 + wr * 64 + mi * 16 + grp * 4;
#pragma unroll
        for (int ni = 0; ni < 4; ++ni) {
            const int f = n0 + wc * 64 + ni * 16 + lr;
            const float bi = bias[f];
            f32x4 vv = acc[mi][ni];
#pragma unroll
            for (int r = 0; r < 4; ++r)
                out[(size_t)(mbase + r) * Ec + f] = vv[r] + bi;
        }
    }
}

// ---------------- attention (r18 champion, unchanged) ------------------------
__global__ __launch_bounds__(256) void attn_kernel(
    const unsigned short* __restrict__ qh, const unsigned short* __restrict__ kh,
    const unsigned short* __restrict__ vt, const float* __restrict__ dmat,
    unsigned short* __restrict__ xh)
{
    __shared__ unsigned short K_lds[2][64 * 64];  // 2 x 8 KB
    __shared__ unsigned short V_lds[2][64 * 64];  // 2 x 8 KB
    __shared__ unsigned short P_lds[4][32][72];   // 18 KB

    const int lin = blockIdx.x;                   // 1024 blocks
    const int j = lin >> 3;
    const int h = j & 7;
    const int qt = (j >> 3) & 7;
    const int b = ((lin & 7) << 1) | (j >> 6);

    const int tid = threadIdx.x;
    const int w = tid >> 6, lane = tid & 63;
    const int lr = lane & 15, grp = lane >> 4;
    const int h8 = lane >> 3, l8 = lane & 7;
    const int q0 = qt * 128;
    const int bh = b * Hc + h;
    const int qw = q0 + w * 32;
    const int kofs = grp * 4;
    const int scol = (l8 ^ h8) * 8;
    const float* dbase0 = dmat + ((size_t)b * Nc + qw + lr) * Nc;
    const float* dbase1 = dbase0 + (size_t)16 * Nc;

    const float LOG2E = 1.4426950408889634f;
    const float SC    = 0.125f * LOG2E;
    const float MC    = -4.0f * LOG2E;

    s16x8 bq0[2], bq1[2];
#pragma unroll
    for (int ks = 0; ks < 2; ++ks) {
        bq0[ks] = *reinterpret_cast<const s16x8*>(
            qh + ((size_t)bh * Nc + qw + lr) * DHc + ks * 32 + grp * 8);
        bq1[ks] = *reinterpret_cast<const s16x8*>(
            qh + ((size_t)bh * Nc + qw + 16 + lr) * DHc + ks * 32 + grp * 8);
    }

    f32x4 acc0[4], acc1[4];
#pragma unroll
    for (int c = 0; c < 4; ++c) { acc0[c] = (f32x4)(0.0f); acc1[c] = (f32x4)(0.0f); }
    float lsum0 = 0.f, lsum1 = 0.f;

    const int NT = Nc / 64;
    i32x4 kst[2], vst[2];
#pragma unroll
    for (int i = 0; i < 2; ++i) {
        const int ch = w + i * 4;
        kst[i] = *reinterpret_cast<const i32x4*>(
            kh + ((size_t)bh * Nc + ch * 8 + h8) * DHc + scol);
        vst[i] = *reinterpret_cast<const i32x4*>(
            vt + ((size_t)bh * DHc + ch * 8 + h8) * Nc + scol);
    }
#pragma unroll
    for (int i = 0; i < 2; ++i) {
        const int ch = w + i * 4;
        *reinterpret_cast<i32x4*>((char*)K_lds[0] + ch * 1024 + lane * 16) = kst[i];
        *reinterpret_cast<i32x4*>((char*)V_lds[0] + ch * 1024 + lane * 16) = vst[i];
    }
#pragma unroll
    for (int i = 0; i < 2; ++i) {
        const int ch = w + i * 4;
        kst[i] = *reinterpret_cast<const i32x4*>(
            kh + ((size_t)bh * Nc + 64 + ch * 8 + h8) * DHc + scol);
        vst[i] = *reinterpret_cast<const i32x4*>(
            vt + ((size_t)bh * DHc + ch * 8 + h8) * Nc + 64 + scol);
    }
    f32x4 dv0[4], dv1[4];
#pragma unroll
    for (int c = 0; c < 4; ++c) {
        dv0[c] = *reinterpret_cast<const f32x4*>(dbase0 + c * 16 + kofs);
        dv1[c] = *reinterpret_cast<const f32x4*>(dbase1 + c * 16 + kofs);
    }

    for (int kt = 0; kt < NT; ++kt) {
        const int cur = kt & 1;
        lds_publish_barrier();
        if (kt + 1 < NT) {
#pragma unroll
            for (int i = 0; i < 2; ++i) {
                const int ch = w + i * 4;
                *reinterpret_cast<i32x4*>((char*)K_lds[cur ^ 1] + ch * 1024 + lane * 16) = kst[i];
                *reinterpret_cast<i32x4*>((char*)V_lds[cur ^ 1] + ch * 1024 + lane * 16) = vst[i];
            }
        }
        if (kt + 2 < NT) {
            const int k2 = (kt + 2) * 64;
#pragma unroll
            for (int i = 0; i < 2; ++i) {
                const int ch = w + i * 4;
                kst[i] = *reinterpret_cast<const i32x4*>(
                    kh + ((size_t)bh * Nc + k2 + ch * 8 + h8) * DHc + scol);
                vst[i] = *reinterpret_cast<const i32x4*>(
                    vt + ((size_t)bh * DHc + ch * 8 + h8) * Nc + k2 + scol);
            }
        }

        f32x4 lgt0[4], lgt1[4];
#pragma unroll
        for (int c = 0; c < 4; ++c) { lgt0[c] = (f32x4)(0.0f); lgt1[c] = (f32x4)(0.0f); }
        __builtin_amdgcn_s_setprio(1);
#pragma unroll
        for (int ks = 0; ks < 2; ++ks) {
#pragma unroll
            for (int c = 0; c < 4; ++c) {
                const int row = c * 16 + lr;
                const int slot = (4 * ks + grp) ^ (lr & 7);
                s16x8 ak = *reinterpret_cast<const s16x8*>(
                    (const char*)K_lds[cur] + row * 128 + slot * 16);
                lgt0[c] = mfma16(ak, bq0[ks], lgt0[c]);
                lgt1[c] = mfma16(ak, bq1[ks], lgt1[c]);
            }
        }
        __builtin_amdgcn_s_setprio(0);
#pragma unroll
        for (int c = 0; c < 4; ++c) {
            s16x4 pk0, pk1;
#pragma unroll
            for (int r = 0; r < 4; ++r) {
                const float dl0 = fmaf(dv0[c][r], LOG2E, MC);
                const float p0 = __builtin_amdgcn_exp2f(fmaf(lgt0[c][r], SC, dl0));
                lsum0 += p0;
                pk0[r] = (short)f2bf(p0 * dv0[c][r]);
                const float dl1 = fmaf(dv1[c][r], LOG2E, MC);
                const float p1 = __builtin_amdgcn_exp2f(fmaf(lgt1[c][r], SC, dl1));
                lsum1 += p1;
                pk1[r] = (short)f2bf(p1 * dv1[c][r]);
            }
            *reinterpret_cast<s16x4*>(&P_lds[w][lr][c * 16 + kofs]) = pk0;
            *reinterpret_cast<s16x4*>(&P_lds[w][16 + lr][c * 16 + kofs]) = pk1;
        }
        if (kt + 1 < NT) {
            const int k1 = (kt + 1) * 64;
#pragma unroll
            for (int c = 0; c < 4; ++c) {
                dv0[c] = *reinterpret_cast<const f32x4*>(dbase0 + k1 + c * 16 + kofs);
                dv1[c] = *reinterpret_cast<const f32x4*>(dbase1 + k1 + c * 16 + kofs);
            }
        }
        __builtin_amdgcn_s_setprio(1);
#pragma unroll
        for (int ks = 0; ks < 2; ++ks) {
            s16x8 pa0 = *reinterpret_cast<const s16x8*>(&P_lds[w][lr][ks * 32 + grp * 8]);
            s16x8 pa1 = *reinterpret_cast<const s16x8*>(&P_lds[w][16 + lr][ks * 32 + grp * 8]);
#pragma unroll
            for (int c = 0; c < 4; ++c) {
                const int row = c * 16 + lr;
                const int slot = (4 * ks + grp) ^ (lr & 7);
                s16x8 bv = *reinterpret_cast<const s16x8*>(
                    (const char*)V_lds[cur] + row * 128 + slot * 16);
                acc0[c] = mfma16(pa0, bv, acc0[c]);
                acc1[c] = mfma16(pa1, bv, acc1[c]);
            }
        }
        __builtin_amdgcn_s_setprio(0);
    }
    lsum0 += __shfl_xor(lsum0, 16, 64);
    lsum0 += __shfl_xor(lsum0, 32, 64);
    lsum1 += __shfl_xor(lsum1, 16, 64);
    lsum1 += __shfl_xor(lsum1, 32, 64);
    const float invd0 = 1.0f / lsum0, invd1 = 1.0f / lsum1;
    float inv0[4], inv1[4];
#pragma unroll
    for (int r = 0; r < 4; ++r) {
        inv0[r] = __shfl(invd0, grp * 4 + r, 64);
        inv1[r] = __shfl(invd1, grp * 4 + r, 64);
    }
#pragma unroll
    for (int c = 0; c < 4; ++c)
#pragma unroll
        for (int r = 0; r < 4; ++r) {
            xh[((size_t)b * Nc + qw + grp * 4 + r) * Ec + h * DHc + c * 16 + lr] =
                f2bf(acc0[c][r] * inv0[r]);
            xh[((size_t)b * Nc + qw + 16 + grp * 4 + r) * Ec + h * DHc + c * 16 + lr] =
                f2bf(acc1[c][r] * inv1[r]);
        }
}

extern "C" void kernel_launch(void* const* d_in, const int* in_sizes, int n_in,
                              void* d_out, int out_size, void* d_ws, size_t ws_size,
                              hipStream_t stream)
{
    (void)in_sizes; (void)n_in; (void)out_size; (void)ws_size;
    const float* q  = (const float*)d_in[0];
    const float* k  = (const float*)d_in[1];
    const float* v  = (const float*)d_in[2];
    const float* dm = (const float*)d_in[3];
    const float* Wq = (const float*)d_in[4];
    const float* bq = (const float*)d_in[5];
    const float* Wk = (const float*)d_in[6];
    const float* bk = (const float*)d_in[7];
    const float* Wv = (const float*)d_in[8];
    const float* bv = (const float*)d_in[9];
    const float* Wp = (const float*)d_in[10];
    const float* bp = (const float*)d_in[11];
    float* out = (float*)d_out;

    const size_t sz = (size_t)Bc * Hc * Nc * DHc;   // 8,388,608 elements
    unsigned short* qhb = (unsigned short*)d_ws;
    unsigned short* khb = qhb + sz;
    unsigned short* vtb = khb + sz;
    unsigned short* xhb = vtb + sz;
    unsigned short* wbf = xhb + sz;                 // 4 x 262144 bf16 = 2 MB

    wcvt_kernel<<<dim3(512), dim3(256), 0, stream>>>(Wq, Wk, Wv, Wp, wbf);
    proj3_kernel<<<dim3(Bc * Nc / 128, Ec / 128, 3), dim3(256), 0, stream>>>(
        q, k, v, wbf, bq, bk, bv, qhb, khb, vtb);
    attn_kernel<<<dim3(Bc * Hc * Nc / 128), dim3(256), 0, stream>>>(
        qhb, khb, vtb, dm, xhb);
    outproj_kernel<<<dim3(Bc * Nc / 128, Ec / 128), dim3(256), 0, stream>>>(
        xhb, wbf + (size_t)3 * 262144, bp, out);
}